// Round 5
// baseline (1547.070 us; speedup 1.0000x reference)
//
#include <hip/hip_runtime.h>
#include <hip/hip_bf16.h>

#define NENT 40000
#define NREL 20
#define DIM 128
#define NBASIS 8
#define NTILE 625              // 40000 / 64 dst-tiles
#define NBIN (NREL * NTILE)    // 12500 (tile, rel) bins
#define SFP 132                // Sf row stride (f32)
#define CAP 1600               // LDS-staged packed entries per tile (avg 1024)

typedef __attribute__((ext_vector_type(8))) short sh8;
typedef __attribute__((ext_vector_type(4))) float fx4;

__device__ __forceinline__ short f2bf(float f) {
    union { __hip_bfloat16 h; short s; } u;
    u.h = __float2bfloat16(f);
    return u.s;
}

// Fragment-order weights: Wf[r][c][kk][lane] = sh8 holding
// W^T[r][col][i..i+7] with col = c*16 + (lane&15), i = kk*32 + (lane>>4)*8.
__global__ void k_wfrag(const float* __restrict__ comp, const float* __restrict__ basis,
                        const float* __restrict__ root,
                        short* __restrict__ Wf, short* __restrict__ rf) {
    int t = blockIdx.x * 256 + threadIdx.x;
    if (t >= DIM * DIM) return;
    int i = t >> 7, o = t & 127;
    float bv[NBASIS];
#pragma unroll
    for (int b = 0; b < NBASIS; ++b) bv[b] = basis[b * 16384 + i * 128 + o];
    int c = o >> 4, l15 = o & 15;
    int kk = i >> 5, lhi = (i >> 3) & 3, e = i & 7;
    int lane = l15 + lhi * 16;
    size_t base = (((size_t)c * 4 + kk) * 64 + lane) * 8 + e;
#pragma unroll
    for (int r = 0; r < NREL; ++r) {
        float s = 0.f;
#pragma unroll
        for (int b = 0; b < NBASIS; ++b) s += comp[r * NBASIS + b] * bv[b];
        Wf[(size_t)r * 16384 + base] = f2bf(s);
    }
    rf[base] = f2bf(root[i * 128 + o]);
}

__global__ void k_hist(const int* __restrict__ et, const int* __restrict__ dst, int E,
                       int* __restrict__ hist, float* __restrict__ deg) {
    int e = blockIdx.x * 256 + threadIdx.x;
    if (e >= E) return;
    int d = dst[e];
    atomicAdd(&hist[(d >> 6) * NREL + et[e]], 1);
    atomicAdd(&deg[d], 1.0f);
}

__global__ void k_scan(const int* __restrict__ hist, int* __restrict__ offs,
                       int* __restrict__ cursor) {
    __shared__ int ps[256];
    int t = threadIdx.x;
    const int chunk = (NBIN + 255) / 256;
    int lo = t * chunk, hi = min(NBIN, lo + chunk);
    int s = 0;
    for (int i = lo; i < hi; ++i) s += hist[i];
    ps[t] = s;
    __syncthreads();
    for (int off = 1; off < 256; off <<= 1) {
        int v = (t >= off) ? ps[t - off] : 0;
        __syncthreads();
        ps[t] += v;
        __syncthreads();
    }
    int run = (t == 0) ? 0 : ps[t - 1];
    for (int i = lo; i < hi; ++i) {
        offs[i] = run;
        cursor[i] = run;
        run += hist[i];
    }
    if (t == 255) offs[NBIN] = run;
}

__global__ void k_scatter(const int* __restrict__ et, const int* __restrict__ srcA,
                          const int* __restrict__ dstA, int E,
                          int* __restrict__ cursor, unsigned* __restrict__ packed) {
    int e = blockIdx.x * 256 + threadIdx.x;
    if (e >= E) return;
    int d = dstA[e];
    int bin = (d >> 6) * NREL + et[e];
    int pos = atomicAdd(&cursor[bin], 1);
    packed[pos] = (unsigned)srcA[e] | ((unsigned)(d & 63) << 16);
}

// issue x-row loads for one relation's window (8 edges/group) into registers.
// Lane c4 loads columns {c4, c4+32, c4+64, c4+96}: stride-1 across lanes.
__device__ __forceinline__ void issue_rel(const float* __restrict__ x,
                                          const unsigned* __restrict__ packed,
                                          const unsigned* __restrict__ pk, int base,
                                          int beg, int end, int g, int c4,
                                          float (*pv)[4], int* pd, int* pn) {
    int rem = end - (beg + g);
    *pn = rem <= 0 ? 0 : (rem >= 57 ? 8 : ((rem + 7) >> 3));
#pragma unroll
    for (int u = 0; u < 8; ++u) {
        int ei = beg + g + u * 8;
        bool ok = ei < end;
        int li = ei - base;
        unsigned p = 0;
        if (ok) p = (li < CAP) ? pk[li] : packed[ei];
        const float* xr = x + (size_t)(p & 0xFFFFu) * DIM + c4;
#pragma unroll
        for (int j = 0; j < 4; ++j) pv[u][j] = xr[j * 32];
        pd[u] = (p >> 16) & 63;
    }
}

// commit prefetched rows into S buffer: conflict-free stride-1 LDS atomics
__device__ __forceinline__ void commit_rel(float (*buf)[SFP], const float (*pv)[4],
                                           const int* pd, int n, int c4) {
#pragma unroll
    for (int u = 0; u < 8; ++u) {
        if (u < n) {
            float* srow = &buf[pd[u]][c4];
#pragma unroll
            for (int j = 0; j < 4; ++j) atomicAdd(srow + j * 32, pv[u][j]);
        }
    }
}

// rare tail for bins with >64 edges: direct load+atomic
__device__ __forceinline__ void tail_rel(const float* __restrict__ x,
                                         const unsigned* __restrict__ packed,
                                         const unsigned* __restrict__ pk, int base,
                                         int beg, int end, int g, int c4,
                                         float (*buf)[SFP]) {
    for (int ei = beg + g + 64; ei < end; ei += 8) {
        int li = ei - base;
        unsigned p = (li < CAP) ? pk[li] : packed[ei];
        const float* xr = x + (size_t)(p & 0xFFFFu) * DIM + c4;
        float* srow = &buf[(p >> 16) & 63][c4];
#pragma unroll
        for (int j = 0; j < 4; ++j) atomicAdd(srow + j * 32, xr[j * 32]);
    }
}

// read A-frags from S and write zeros back
__device__ __forceinline__ void afrag_rdzero(float (*S)[SFP], int wr0, int l15, int lhi,
                                             sh8* a) {
    const float4 z = make_float4(0.f, 0.f, 0.f, 0.f);
#pragma unroll
    for (int kk = 0; kk < 4; ++kk) {
        float* ap = &S[wr0 + l15][kk * 32 + lhi * 8];
        float4 lo = *(float4*)ap;
        float4 hi = *(float4*)(ap + 4);
        *(float4*)ap = z;
        *(float4*)(ap + 4) = z;
        sh8 vv;
        vv[0] = f2bf(lo.x); vv[1] = f2bf(lo.y); vv[2] = f2bf(lo.z); vv[3] = f2bf(lo.w);
        vv[4] = f2bf(hi.x); vv[5] = f2bf(hi.y); vv[6] = f2bf(hi.z); vv[7] = f2bf(hi.w);
        a[kk] = vv;
    }
}

__device__ __forceinline__ void afrag_rd(const float (*S)[SFP], int wr0, int l15, int lhi,
                                         sh8* a) {
#pragma unroll
    for (int kk = 0; kk < 4; ++kk) {
        const float* ap = &S[wr0 + l15][kk * 32 + lhi * 8];
        float4 lo = *(const float4*)ap;
        float4 hi = *(const float4*)(ap + 4);
        sh8 vv;
        vv[0] = f2bf(lo.x); vv[1] = f2bf(lo.y); vv[2] = f2bf(lo.z); vv[3] = f2bf(lo.w);
        vv[4] = f2bf(hi.x); vv[5] = f2bf(hi.y); vv[6] = f2bf(hi.z); vv[7] = f2bf(hi.w);
        a[kk] = vv;
    }
}

__device__ __forceinline__ void mfma_rel(const sh8* a, const sh8* W8, int lane, fx4* acc) {
#pragma unroll
    for (int c = 0; c < 8; ++c) {
#pragma unroll
        for (int kk = 0; kk < 4; ++kk) {
            sh8 b = W8[(c * 4 + kk) * 64 + lane];
            acc[c] = __builtin_amdgcn_mfma_f32_16x16x32_bf16(a[kk], b, acc[c], 0, 0, 0);
        }
    }
}

// Fused RGCN layer: tile-contiguous edges staged in LDS, 2-round register
// prefetch pipeline, conflict-free gather atomics, double-buffered Sf,
// 1 barrier/relation, B-fragments straight from global.
__global__ __launch_bounds__(256) void k_rgcn_mfma(
    const float* __restrict__ x, const short* __restrict__ Wf,
    const short* __restrict__ rf, const float* __restrict__ bias,
    const unsigned* __restrict__ packed, const int* __restrict__ offs,
    const float* __restrict__ deg, float* __restrict__ out, int act) {
    __shared__ __align__(16) float Sf[2][64][SFP];
    __shared__ __align__(16) unsigned pk[CAP];
    __shared__ int ro[NREL + 1];

    int tile = blockIdx.x, t0 = tile * 64;
    int t = threadIdx.x;
    int lane = t & 63, wid = t >> 6, wr0 = wid * 16;
    int l15 = lane & 15, lhi = lane >> 4;
    int g = t >> 5, c4 = t & 31;

    if (t <= NREL) ro[t] = offs[tile * NREL + t];
    {
        const float4 z = make_float4(0.f, 0.f, 0.f, 0.f);
        float4* p = (float4*)&Sf[0][0][0];
        for (int i = t; i < 2 * 64 * SFP / 4; i += 256) p[i] = z;
    }
    __syncthreads();
    int base = ro[0];
    int total = ro[NREL] - base;
    for (int i = t; i < total && i < CAP; i += 256) pk[i] = packed[base + i];
    __syncthreads();

    fx4 acc[8];
#pragma unroll
    for (int c = 0; c < 8; ++c) acc[c] = (fx4){0.f, 0.f, 0.f, 0.f};

    float pvA[8][4], pvB[8][4];
    int pdA[8], pdB[8], nA, nB;

    // prologue: rel 0 -> buf0 directly; rel 1 prefetched into B
    issue_rel(x, packed, pk, base, ro[0], ro[1], g, c4, pvA, pdA, &nA);
    commit_rel(Sf[0], pvA, pdA, nA, c4);
    tail_rel(x, packed, pk, base, ro[0], ro[1], g, c4, Sf[0]);
    issue_rel(x, packed, pk, base, ro[1], ro[2], g, c4, pvB, pdB, &nB);
    __syncthreads();   // buf0 visible to all; B loads drained

    for (int r = 0; r < NREL; r += 2) {
        // even round: cur=Sf[0], pending=B(r+1), spare=A <- issue(r+2)
        {
            float (*cur)[SFP] = Sf[0];
            float (*nxt)[SFP] = Sf[1];
            if (r + 2 < NREL)
                issue_rel(x, packed, pk, base, ro[r + 2], ro[r + 3], g, c4, pvA, pdA, &nA);
            sh8 a[4];
            afrag_rdzero(cur, wr0, l15, lhi, a);
            mfma_rel(a, (const sh8*)(Wf + (size_t)r * 16384), lane, acc);
            if (r + 1 < NREL) {
                commit_rel(nxt, pvB, pdB, nB, c4);
                tail_rel(x, packed, pk, base, ro[r + 1], ro[r + 2], g, c4, nxt);
            }
            __syncthreads();
        }
        // odd round: cur=Sf[1], pending=A(r+2), spare=B <- issue(r+3)
        if (r + 1 < NREL) {
            float (*cur)[SFP] = Sf[1];
            float (*nxt)[SFP] = Sf[0];
            if (r + 3 < NREL)
                issue_rel(x, packed, pk, base, ro[r + 3], ro[r + 4], g, c4, pvB, pdB, &nB);
            sh8 a[4];
            afrag_rdzero(cur, wr0, l15, lhi, a);
            mfma_rel(a, (const sh8*)(Wf + (size_t)(r + 1) * 16384), lane, acc);
            if (r + 2 < NREL) {
                commit_rel(nxt, pvA, pdA, nA, c4);
                tail_rel(x, packed, pk, base, ro[r + 2], ro[r + 3], g, c4, nxt);
            }
            __syncthreads();
        }
    }

    // mean over in-degree (C/D row = lhi*4 + j)
    float invd[4];
#pragma unroll
    for (int j = 0; j < 4; ++j) {
        float dg = deg[t0 + wr0 + lhi * 4 + j];
        invd[j] = 1.f / (dg < 1.f ? 1.f : dg);
    }
#pragma unroll
    for (int c = 0; c < 8; ++c)
#pragma unroll
        for (int j = 0; j < 4; ++j) acc[c][j] *= invd[j];

    // root GEMM: stage own x rows into Sf[0], frags from rf
    {
        float (*S0)[SFP] = Sf[0];
#pragma unroll
        for (int p = 0; p < 8; ++p) {
            int rr = g + p * 8;
            *(float4*)(&S0[rr][c4 * 4]) =
                *(const float4*)(x + (size_t)(t0 + rr) * DIM + c4 * 4);
        }
        __syncthreads();
        sh8 a[4];
        afrag_rd(S0, wr0, l15, lhi, a);
        mfma_rel(a, (const sh8*)rf, lane, acc);
    }

    // bias + act + store
#pragma unroll
    for (int c = 0; c < 8; ++c) {
        int col = c * 16 + l15;
        float bv = bias[col];
#pragma unroll
        for (int j = 0; j < 4; ++j) {
            float v = acc[c][j] + bv;
            if (act) v = tanhf(v);
            out[(size_t)(t0 + wr0 + lhi * 4 + j) * DIM + col] = v;
        }
    }
}

__global__ void k_rel(const float* __restrict__ rel, const float* __restrict__ wrel,
                      float* __restrict__ out, int nrows) {
    int idx = blockIdx.x * 256 + threadIdx.x;
    if (idx >= nrows * DIM) return;
    int j = idx >> 7, o = idx & 127;
    float s = 0.f;
    for (int i = 0; i < DIM; ++i) s += rel[j * DIM + i] * wrel[i * DIM + o];
    out[idx] = s;
}

extern "C" void kernel_launch(void* const* d_in, const int* in_sizes, int n_in,
                              void* d_out, int out_size, void* d_ws, size_t ws_size,
                              hipStream_t stream) {
    const int* edge_index = (const int*)d_in[0];
    const int* edge_type  = (const int*)d_in[1];
    const float* init_embed = (const float*)d_in[2];
    const float* init_rel   = (const float*)d_in[3];
    const float* w_rel      = (const float*)d_in[4];
    const float* comp1  = (const float*)d_in[5];
    const float* basis1 = (const float*)d_in[6];
    const float* root1  = (const float*)d_in[7];
    const float* bias1  = (const float*)d_in[8];
    const float* comp2  = (const float*)d_in[9];
    const float* basis2 = (const float*)d_in[10];
    const float* root2  = (const float*)d_in[11];
    const float* bias2  = (const float*)d_in[12];

    int E = in_sizes[1];
    const int* src = edge_index;
    const int* dst = edge_index + E;
    int relrows = in_sizes[3] / DIM;   // 40

    // workspace layout (16B-aligned regions)
    short* Wf1 = (short*)d_ws;                           // 20*16384 shorts
    short* Wf2 = Wf1 + (size_t)NREL * 16384;
    short* rf1 = Wf2 + (size_t)NREL * 16384;             // 16384
    short* rf2 = rf1 + 16384;
    float* h   = (float*)(rf2 + 16384);                  // 40000*128
    float* deg = h + (size_t)NENT * DIM;                 // 40000
    int* hist     = (int*)(deg + NENT);                  // pad 12512
    int* offs     = hist + 12512;
    int* cursor   = offs + 12512;
    unsigned* packed = (unsigned*)(cursor + 12512);      // E

    float* outx = (float*)d_out;
    float* outr = outx + (size_t)NENT * DIM;

    hipMemsetAsync(hist, 0, NBIN * sizeof(int), stream);
    hipMemsetAsync(deg, 0, NENT * sizeof(float), stream);

    k_wfrag<<<64, 256, 0, stream>>>(comp1, basis1, root1, Wf1, rf1);
    k_wfrag<<<64, 256, 0, stream>>>(comp2, basis2, root2, Wf2, rf2);
    k_hist<<<(E + 255) / 256, 256, 0, stream>>>(edge_type, dst, E, hist, deg);
    k_scan<<<1, 256, 0, stream>>>(hist, offs, cursor);
    k_scatter<<<(E + 255) / 256, 256, 0, stream>>>(edge_type, src, dst, E, cursor, packed);

    // layer 1: h = tanh(S@W1/deg + x@root1 + bias1)
    k_rgcn_mfma<<<NTILE, 256, 0, stream>>>(init_embed, Wf1, rf1, bias1,
                                           packed, offs, deg, h, 1);
    // layer 2: out = S@W2/deg + h@root2 + bias2
    k_rgcn_mfma<<<NTILE, 256, 0, stream>>>(h, Wf2, rf2, bias2,
                                           packed, offs, deg, outx, 0);

    // relation output: r = init_rel @ w_rel
    k_rel<<<(relrows * DIM + 255) / 256, 256, 0, stream>>>(init_rel, w_rel, outr, relrows);
}

// Round 6
// 587.160 us; speedup vs baseline: 2.6348x; 2.6348x over previous
//
#include <hip/hip_runtime.h>
#include <hip/hip_bf16.h>

#define NENT 40000
#define NREL 20
#define DIM 128
#define NBASIS 8
#define KTOT 1152              // 8*128 (G) + 128 (x)
#define P0END 20480            // pass split (320 tiles of 64)

typedef __attribute__((ext_vector_type(8))) short sh8;
typedef __attribute__((ext_vector_type(4))) float fx4;

__device__ __forceinline__ short f2bf(float f) {
    union { __hip_bfloat16 h; short s; } u;
    u.h = __float2bfloat16(f);
    return u.s;
}

// f32 -> bf16 copy (x panel for layer 1 + gather source)
__global__ void k_tobf(const float* __restrict__ x, ushort* __restrict__ xb, int nelem) {
    int i = (blockIdx.x * 256 + threadIdx.x) * 4;
    if (i >= nelem) return;
    float4 v = *(const float4*)(x + i);
    ushort4 o;
    o.x = (ushort)f2bf(v.x); o.y = (ushort)f2bf(v.y);
    o.z = (ushort)f2bf(v.z); o.w = (ushort)f2bf(v.w);
    *(ushort4*)(xb + i) = o;
}

// Fragment-order stacked B: ks 0..7 = basis[ks] (k-rows i), ks 8 = root.
// B-frag: lane holds B[k = kk*32 + lhi*8 + e][col = c*16 + l15].
__global__ void k_wfrag9(const float* __restrict__ basis, const float* __restrict__ root,
                         short* __restrict__ Wfb) {
    int t = blockIdx.x * 256 + threadIdx.x;
    if (t >= 9 * 16384) return;
    int ks = t / 16384;
    int rem = t & 16383;
    int i = rem >> 7, o = rem & 127;
    float v = (ks < 8) ? basis[ks * 16384 + i * 128 + o] : root[i * 128 + o];
    int c = o >> 4, l15 = o & 15;
    int kk = i >> 5, lhi = (i >> 3) & 3, e = i & 7;
    int lane = l15 + lhi * 16;
    Wfb[(size_t)ks * 16384 + (size_t)(((c * 4 + kk) * 64 + lane) << 3) + e] = f2bf(v);
}

__global__ void k_hist(const int* __restrict__ dst, int E, int* __restrict__ hist) {
    int e = blockIdx.x * 256 + threadIdx.x;
    if (e < E) atomicAdd(&hist[dst[e]], 1);
}

// exclusive scan over NENT bins, single block
__global__ void k_scan(const int* __restrict__ hist, int* __restrict__ offs,
                       int* __restrict__ cursor) {
    __shared__ int ps[256];
    int t = threadIdx.x;
    const int chunk = (NENT + 255) / 256;   // 157
    int lo = t * chunk, hi = min(NENT, lo + chunk);
    int s = 0;
    for (int i = lo; i < hi; ++i) s += hist[i];
    ps[t] = s;
    __syncthreads();
    for (int off = 1; off < 256; off <<= 1) {
        int v = (t >= off) ? ps[t - off] : 0;
        __syncthreads();
        ps[t] += v;
        __syncthreads();
    }
    int run = (t == 0) ? 0 : ps[t - 1];
    for (int i = lo; i < hi; ++i) {
        offs[i] = run;
        cursor[i] = run;
        run += hist[i];
    }
    if (t == 255) offs[NENT] = run;
}

// counting-sort by dst: packed = src | et<<16  (src < 65536, et < 32)
__global__ void k_scatter(const int* __restrict__ et, const int* __restrict__ srcA,
                          const int* __restrict__ dstA, int E,
                          int* __restrict__ cursor, unsigned* __restrict__ packed) {
    int e = blockIdx.x * 256 + threadIdx.x;
    if (e >= E) return;
    int pos = atomicAdd(&cursor[dstA[e]], 1);
    packed[pos] = (unsigned)srcA[e] | ((unsigned)et[e] << 16);
}

// One wave per dst node: G[n][b][:] = (1/deg) * sum_e comp[et,b]*x[src].
// All accumulation in registers; depth-2 prefetch; bf16 in, bf16 out.
__global__ __launch_bounds__(256) void k_gather(
    const ushort* __restrict__ xb, const unsigned* __restrict__ packed,
    const int* __restrict__ offs, const float* __restrict__ comp,
    ushort* __restrict__ G, int n0, int n1) {
    __shared__ __align__(16) float cl[NREL * NBASIS];
    int t = threadIdx.x;
    if (t < NREL * NBASIS) cl[t] = comp[t];
    __syncthreads();
    int n = n0 + blockIdx.x * 4 + (t >> 6);
    if (n >= n1) return;
    int lane = t & 63;                       // owns cols {2*lane, 2*lane+1}
    int beg = offs[n];
    int cnt = offs[n + 1] - beg;

    float a0[NBASIS], a1[NBASIS];
#pragma unroll
    for (int b = 0; b < NBASIS; ++b) { a0[b] = 0.f; a1[b] = 0.f; }

    const unsigned* xrow = (const unsigned*)xb + lane;   // +row*64 per row
    unsigned pA = 0, pB = 0, rA = 0;
    if (cnt > 0) { pA = packed[beg]; rA = xrow[(size_t)(pA & 0xFFFFu) * 64]; }
    if (cnt > 1) pB = packed[beg + 1];

    for (int i = 0; i < cnt; ++i) {
        unsigned pC = (i + 2 < cnt) ? packed[beg + i + 2] : 0u;
        unsigned rB = xrow[(size_t)(pB & 0xFFFFu) * 64];   // prefetch next row
        float xlo = __uint_as_float(rA << 16);
        float xhi = __uint_as_float(rA & 0xFFFF0000u);
        int et = pA >> 16;
        float4 cwa = *(const float4*)&cl[et * NBASIS];
        float4 cwb = *(const float4*)&cl[et * NBASIS + 4];
        a0[0] += cwa.x * xlo; a1[0] += cwa.x * xhi;
        a0[1] += cwa.y * xlo; a1[1] += cwa.y * xhi;
        a0[2] += cwa.z * xlo; a1[2] += cwa.z * xhi;
        a0[3] += cwa.w * xlo; a1[3] += cwa.w * xhi;
        a0[4] += cwb.x * xlo; a1[4] += cwb.x * xhi;
        a0[5] += cwb.y * xlo; a1[5] += cwb.y * xhi;
        a0[6] += cwb.z * xlo; a1[6] += cwb.z * xhi;
        a0[7] += cwb.w * xlo; a1[7] += cwb.w * xhi;
        pA = pB; pB = pC; rA = rB;
    }

    float inv = 1.f / (float)(cnt < 1 ? 1 : cnt);
    unsigned* go = (unsigned*)(G + (size_t)(n - n0) * 1024) + lane;
#pragma unroll
    for (int b = 0; b < NBASIS; ++b) {
        unsigned lo = (unsigned)(ushort)f2bf(a0[b] * inv);
        unsigned hi = (unsigned)(ushort)f2bf(a1[b] * inv);
        go[b * 64] = lo | (hi << 16);
    }
}

// Dense MFMA GEMM: C[64 x 128] = [G(1024) | xpan(128)] @ Wfb(1152x128) + bias.
// A-frags direct from global (no reuse), B-frags fragment-order (L2-hot).
__global__ __launch_bounds__(256) void k_bgemm(
    const ushort* __restrict__ G, const ushort* __restrict__ xpan,
    const short* __restrict__ Wfb, const float* __restrict__ bias,
    ushort* __restrict__ outbf, float* __restrict__ outf, int n0, int act) {
    int t = threadIdx.x;
    int lane = t & 63, wid = t >> 6;
    int l15 = lane & 15, lhi = lane >> 4;
    int arow = n0 + blockIdx.x * 64 + wid * 16 + l15;

    fx4 acc[8];
#pragma unroll
    for (int c = 0; c < 8; ++c) acc[c] = (fx4){0.f, 0.f, 0.f, 0.f};

    const ushort* Ar = G + (size_t)(arow - n0) * 1024 + lhi * 8;
    const ushort* Xr = xpan + (size_t)arow * 128 + lhi * 8;

#pragma unroll
    for (int ks = 0; ks < 9; ++ks) {
        sh8 a[4];
        if (ks < 8) {
#pragma unroll
            for (int kk = 0; kk < 4; ++kk) a[kk] = *(const sh8*)(Ar + ks * 128 + kk * 32);
        } else {
#pragma unroll
            for (int kk = 0; kk < 4; ++kk) a[kk] = *(const sh8*)(Xr + kk * 32);
        }
        const sh8* W8 = (const sh8*)(Wfb + (size_t)ks * 16384);
#pragma unroll
        for (int c = 0; c < 8; ++c) {
#pragma unroll
            for (int kk = 0; kk < 4; ++kk) {
                sh8 b = W8[(c * 4 + kk) * 64 + lane];
                acc[c] = __builtin_amdgcn_mfma_f32_16x16x32_bf16(a[kk], b, acc[c], 0, 0, 0);
            }
        }
    }

    int orow0 = n0 + blockIdx.x * 64 + wid * 16 + lhi * 4;
#pragma unroll
    for (int c = 0; c < 8; ++c) {
        int col = c * 16 + l15;
        float bv = bias[col];
#pragma unroll
        for (int j = 0; j < 4; ++j) {
            float v = acc[c][j] + bv;
            if (act) {
                v = tanhf(v);
                outbf[(size_t)(orow0 + j) * 128 + col] = (ushort)f2bf(v);
            } else {
                outf[(size_t)(orow0 + j) * 128 + col] = v;
            }
        }
    }
}

__global__ void k_rel(const float* __restrict__ rel, const float* __restrict__ wrel,
                      float* __restrict__ out, int nrows) {
    int idx = blockIdx.x * 256 + threadIdx.x;
    if (idx >= nrows * DIM) return;
    int j = idx >> 7, o = idx & 127;
    float s = 0.f;
    for (int i = 0; i < DIM; ++i) s += rel[j * DIM + i] * wrel[i * DIM + o];
    out[idx] = s;
}

extern "C" void kernel_launch(void* const* d_in, const int* in_sizes, int n_in,
                              void* d_out, int out_size, void* d_ws, size_t ws_size,
                              hipStream_t stream) {
    const int* edge_index = (const int*)d_in[0];
    const int* edge_type  = (const int*)d_in[1];
    const float* init_embed = (const float*)d_in[2];
    const float* init_rel   = (const float*)d_in[3];
    const float* w_rel      = (const float*)d_in[4];
    const float* comp1  = (const float*)d_in[5];
    const float* basis1 = (const float*)d_in[6];
    const float* root1  = (const float*)d_in[7];
    const float* bias1  = (const float*)d_in[8];
    const float* comp2  = (const float*)d_in[9];
    const float* basis2 = (const float*)d_in[10];
    const float* root2  = (const float*)d_in[11];
    const float* bias2  = (const float*)d_in[12];

    int E = in_sizes[1];
    const int* src = edge_index;
    const int* dst = edge_index + E;
    int relrows = in_sizes[3] / DIM;   // 40

    // workspace layout (16B-aligned regions)
    short* Wfb1 = (short*)d_ws;                          // 9*16384 shorts
    short* Wfb2 = Wfb1 + (size_t)9 * 16384;
    ushort* xb  = (ushort*)(Wfb2 + (size_t)9 * 16384);   // 40000*128 bf16
    ushort* hb  = xb + (size_t)NENT * DIM;               // 40000*128 bf16
    ushort* G   = hb + (size_t)NENT * DIM;               // 20480*1024 bf16 (42 MB)
    int* hist   = (int*)(G + (size_t)P0END * 1024);      // 40000 (pad 40004)
    int* offs   = hist + 40004;                          // 40001 (pad 40004)
    int* cursor = offs + 40004;                          // 40000 (pad 40004)
    unsigned* packed = (unsigned*)(cursor + 40004);      // E

    float* outx = (float*)d_out;
    float* outr = outx + (size_t)NENT * DIM;

    hipMemsetAsync(hist, 0, NENT * sizeof(int), stream);

    k_tobf<<<(NENT * DIM / 4 + 255) / 256, 256, 0, stream>>>(init_embed, xb, NENT * DIM);
    k_wfrag9<<<(9 * 16384 + 255) / 256, 256, 0, stream>>>(basis1, root1, Wfb1);
    k_wfrag9<<<(9 * 16384 + 255) / 256, 256, 0, stream>>>(basis2, root2, Wfb2);
    k_hist<<<(E + 255) / 256, 256, 0, stream>>>(dst, E, hist);
    k_scan<<<1, 256, 0, stream>>>(hist, offs, cursor);
    k_scatter<<<(E + 255) / 256, 256, 0, stream>>>(edge_type, src, dst, E, cursor, packed);

    // layer 1: hb = bf16(tanh(G@W~1 + x@root1 + bias1)), two node passes
    k_gather<<<P0END / 4, 256, 0, stream>>>(xb, packed, offs, comp1, G, 0, P0END);
    k_bgemm<<<P0END / 64, 256, 0, stream>>>(G, xb, Wfb1, bias1, hb, outx, 0, 1);
    k_gather<<<(NENT - P0END) / 4, 256, 0, stream>>>(xb, packed, offs, comp1, G, P0END, NENT);
    k_bgemm<<<(NENT - P0END) / 64, 256, 0, stream>>>(G, xb, Wfb1, bias1, hb, outx, P0END, 1);

    // layer 2: out = G@W~2 + h@root2 + bias2 (f32 to d_out)
    k_gather<<<P0END / 4, 256, 0, stream>>>(hb, packed, offs, comp2, G, 0, P0END);
    k_bgemm<<<P0END / 64, 256, 0, stream>>>(G, hb, Wfb2, bias2, hb, outx, 0, 0);
    k_gather<<<(NENT - P0END) / 4, 256, 0, stream>>>(hb, packed, offs, comp2, G, P0END, NENT);
    k_bgemm<<<(NENT - P0END) / 64, 256, 0, stream>>>(G, hb, Wfb2, bias2, hb, outx, P0END, 0);

    // relation output: r = init_rel @ w_rel
    k_rel<<<(relrows * DIM + 255) / 256, 256, 0, stream>>>(init_rel, w_rel, outr, relrows);
}

// Round 7
// 510.060 us; speedup vs baseline: 3.0331x; 1.1512x over previous
//
#include <hip/hip_runtime.h>
#include <hip/hip_bf16.h>

#define NENT 40000
#define NREL 20
#define DIM 128
#define NBASIS 8
#define KTOT 1152              // 8*128 (G) + 128 (x)
#define P0END 20480            // pass split (320 tiles of 64)
#define SCANBLK 157            // ceil(40000/256)

typedef __attribute__((ext_vector_type(8))) short sh8;
typedef __attribute__((ext_vector_type(4))) float fx4;

__device__ __forceinline__ short f2bf(float f) {
    union { __hip_bfloat16 h; short s; } u;
    u.h = __float2bfloat16(f);
    return u.s;
}

// f32 -> bf16 copy (x panel for layer 1 + gather source)
__global__ void k_tobf(const float* __restrict__ x, ushort* __restrict__ xb, int nelem) {
    int i = (blockIdx.x * 256 + threadIdx.x) * 4;
    if (i >= nelem) return;
    float4 v = *(const float4*)(x + i);
    ushort4 o;
    o.x = (ushort)f2bf(v.x); o.y = (ushort)f2bf(v.y);
    o.z = (ushort)f2bf(v.z); o.w = (ushort)f2bf(v.w);
    *(ushort4*)(xb + i) = o;
}

// Fragment-order stacked B: ks 0..7 = basis[ks] (k-rows i), ks 8 = root.
// B-frag: lane holds B[k = kk*32 + lhi*8 + e][col = c*16 + l15].
__global__ void k_wfrag9(const float* __restrict__ basis, const float* __restrict__ root,
                         short* __restrict__ Wfb) {
    int t = blockIdx.x * 256 + threadIdx.x;
    if (t >= 9 * 16384) return;
    int ks = t / 16384;
    int rem = t & 16383;
    int i = rem >> 7, o = rem & 127;
    float v = (ks < 8) ? basis[ks * 16384 + i * 128 + o] : root[i * 128 + o];
    int c = o >> 4, l15 = o & 15;
    int kk = i >> 5, lhi = (i >> 3) & 3, e = i & 7;
    int lane = l15 + lhi * 16;
    Wfb[(size_t)ks * 16384 + (size_t)(((c * 4 + kk) * 64 + lane) << 3) + e] = f2bf(v);
}

__global__ void k_hist(const int* __restrict__ dst, int E, int* __restrict__ hist) {
    int e = blockIdx.x * 256 + threadIdx.x;
    if (e < E) atomicAdd(&hist[dst[e]], 1);
}

// -------- 3-phase parallel scan over NENT bins --------
// phase 1: per-block exclusive prefixes + block sums
__global__ void k_scan1(const int* __restrict__ hist, int* __restrict__ offs,
                        int* __restrict__ bsum) {
    __shared__ int ps[256];
    int t = threadIdx.x;
    int i = blockIdx.x * 256 + t;
    int v = (i < NENT) ? hist[i] : 0;
    ps[t] = v;
    __syncthreads();
    for (int off = 1; off < 256; off <<= 1) {
        int u = (t >= off) ? ps[t - off] : 0;
        __syncthreads();
        ps[t] += u;
        __syncthreads();
    }
    if (i < NENT) offs[i] = ps[t] - v;          // exclusive within block
    if (t == 255) bsum[blockIdx.x] = ps[255];   // block total
}

// phase 2: exclusive scan of the block sums (157 values, one block)
__global__ void k_scan2(int* __restrict__ bsum) {
    __shared__ int ps[256];
    int t = threadIdx.x;
    int v = (t < SCANBLK) ? bsum[t] : 0;
    ps[t] = v;
    __syncthreads();
    for (int off = 1; off < 256; off <<= 1) {
        int u = (t >= off) ? ps[t - off] : 0;
        __syncthreads();
        ps[t] += u;
        __syncthreads();
    }
    if (t < SCANBLK) bsum[t] = ps[t] - v;       // exclusive
}

// phase 3: add block offsets, emit offs + cursor, offs[NENT]=E
__global__ void k_scan3(int* __restrict__ offs, int* __restrict__ cursor,
                        const int* __restrict__ bsum, int E) {
    int i = blockIdx.x * 256 + threadIdx.x;
    if (i < NENT) {
        int o = offs[i] + bsum[blockIdx.x];
        offs[i] = o;
        cursor[i] = o;
    }
    if (i == 0) offs[NENT] = E;
}

// counting-sort by dst: packed = src | et<<16  (src < 65536, et < 32)
__global__ void k_scatter(const int* __restrict__ et, const int* __restrict__ srcA,
                          const int* __restrict__ dstA, int E,
                          int* __restrict__ cursor, unsigned* __restrict__ packed) {
    int e = blockIdx.x * 256 + threadIdx.x;
    if (e >= E) return;
    int pos = atomicAdd(&cursor[dstA[e]], 1);
    packed[pos] = (unsigned)srcA[e] | ((unsigned)et[e] << 16);
}

// One wave per dst node: G[n][b][:] = (1/deg) * sum_e comp[et,b]*x[src].
// All accumulation in registers; depth-2 prefetch; bf16 in, bf16 out.
__global__ __launch_bounds__(256) void k_gather(
    const ushort* __restrict__ xb, const unsigned* __restrict__ packed,
    const int* __restrict__ offs, const float* __restrict__ comp,
    ushort* __restrict__ G, int n0, int n1) {
    __shared__ __align__(16) float cl[NREL * NBASIS];
    int t = threadIdx.x;
    if (t < NREL * NBASIS) cl[t] = comp[t];
    __syncthreads();
    int n = n0 + blockIdx.x * 4 + (t >> 6);
    if (n >= n1) return;
    int lane = t & 63;                       // owns cols {2*lane, 2*lane+1}
    int beg = offs[n];
    int cnt = offs[n + 1] - beg;

    float a0[NBASIS], a1[NBASIS];
#pragma unroll
    for (int b = 0; b < NBASIS; ++b) { a0[b] = 0.f; a1[b] = 0.f; }

    const unsigned* xrow = (const unsigned*)xb + lane;   // +row*64 per row
    unsigned pA = 0, pB = 0, rA = 0;
    if (cnt > 0) { pA = packed[beg]; rA = xrow[(size_t)(pA & 0xFFFFu) * 64]; }
    if (cnt > 1) pB = packed[beg + 1];

    for (int i = 0; i < cnt; ++i) {
        unsigned pC = (i + 2 < cnt) ? packed[beg + i + 2] : 0u;
        unsigned rB = xrow[(size_t)(pB & 0xFFFFu) * 64];   // prefetch next row
        float xlo = __uint_as_float(rA << 16);
        float xhi = __uint_as_float(rA & 0xFFFF0000u);
        int et = pA >> 16;
        float4 cwa = *(const float4*)&cl[et * NBASIS];
        float4 cwb = *(const float4*)&cl[et * NBASIS + 4];
        a0[0] += cwa.x * xlo; a1[0] += cwa.x * xhi;
        a0[1] += cwa.y * xlo; a1[1] += cwa.y * xhi;
        a0[2] += cwa.z * xlo; a1[2] += cwa.z * xhi;
        a0[3] += cwa.w * xlo; a1[3] += cwa.w * xhi;
        a0[4] += cwb.x * xlo; a1[4] += cwb.x * xhi;
        a0[5] += cwb.y * xlo; a1[5] += cwb.y * xhi;
        a0[6] += cwb.z * xlo; a1[6] += cwb.z * xhi;
        a0[7] += cwb.w * xlo; a1[7] += cwb.w * xhi;
        pA = pB; pB = pC; rA = rB;
    }

    float inv = 1.f / (float)(cnt < 1 ? 1 : cnt);
    unsigned* go = (unsigned*)(G + (size_t)(n - n0) * 1024) + lane;
#pragma unroll
    for (int b = 0; b < NBASIS; ++b) {
        unsigned lo = (unsigned)(ushort)f2bf(a0[b] * inv);
        unsigned hi = (unsigned)(ushort)f2bf(a1[b] * inv);
        go[b * 64] = lo | (hi << 16);
    }
}

// Dense MFMA GEMM: C[64 x 128] = [G(1024) | xpan(128)] @ Wfb(1152x128) + bias.
// A-frags direct from global (no reuse), B-frags fragment-order (L2-hot).
__global__ __launch_bounds__(256) void k_bgemm(
    const ushort* __restrict__ G, const ushort* __restrict__ xpan,
    const short* __restrict__ Wfb, const float* __restrict__ bias,
    ushort* __restrict__ outbf, float* __restrict__ outf, int n0, int act) {
    int t = threadIdx.x;
    int lane = t & 63, wid = t >> 6;
    int l15 = lane & 15, lhi = lane >> 4;
    int arow = n0 + blockIdx.x * 64 + wid * 16 + l15;

    fx4 acc[8];
#pragma unroll
    for (int c = 0; c < 8; ++c) acc[c] = (fx4){0.f, 0.f, 0.f, 0.f};

    const ushort* Ar = G + (size_t)(arow - n0) * 1024 + lhi * 8;
    const ushort* Xr = xpan + (size_t)arow * 128 + lhi * 8;

#pragma unroll
    for (int ks = 0; ks < 9; ++ks) {
        sh8 a[4];
        if (ks < 8) {
#pragma unroll
            for (int kk = 0; kk < 4; ++kk) a[kk] = *(const sh8*)(Ar + ks * 128 + kk * 32);
        } else {
#pragma unroll
            for (int kk = 0; kk < 4; ++kk) a[kk] = *(const sh8*)(Xr + kk * 32);
        }
        const sh8* W8 = (const sh8*)(Wfb + (size_t)ks * 16384);
#pragma unroll
        for (int c = 0; c < 8; ++c) {
#pragma unroll
            for (int kk = 0; kk < 4; ++kk) {
                sh8 b = W8[(c * 4 + kk) * 64 + lane];
                acc[c] = __builtin_amdgcn_mfma_f32_16x16x32_bf16(a[kk], b, acc[c], 0, 0, 0);
            }
        }
    }

    int orow0 = n0 + blockIdx.x * 64 + wid * 16 + lhi * 4;
#pragma unroll
    for (int c = 0; c < 8; ++c) {
        int col = c * 16 + l15;
        float bv = bias[col];
#pragma unroll
        for (int j = 0; j < 4; ++j) {
            float v = acc[c][j] + bv;
            if (act) {
                v = tanhf(v);
                outbf[(size_t)(orow0 + j) * 128 + col] = (ushort)f2bf(v);
            } else {
                outf[(size_t)(orow0 + j) * 128 + col] = v;
            }
        }
    }
}

__global__ void k_rel(const float* __restrict__ rel, const float* __restrict__ wrel,
                      float* __restrict__ out, int nrows) {
    int idx = blockIdx.x * 256 + threadIdx.x;
    if (idx >= nrows * DIM) return;
    int j = idx >> 7, o = idx & 127;
    float s = 0.f;
    for (int i = 0; i < DIM; ++i) s += rel[j * DIM + i] * wrel[i * DIM + o];
    out[idx] = s;
}

extern "C" void kernel_launch(void* const* d_in, const int* in_sizes, int n_in,
                              void* d_out, int out_size, void* d_ws, size_t ws_size,
                              hipStream_t stream) {
    const int* edge_index = (const int*)d_in[0];
    const int* edge_type  = (const int*)d_in[1];
    const float* init_embed = (const float*)d_in[2];
    const float* init_rel   = (const float*)d_in[3];
    const float* w_rel      = (const float*)d_in[4];
    const float* comp1  = (const float*)d_in[5];
    const float* basis1 = (const float*)d_in[6];
    const float* root1  = (const float*)d_in[7];
    const float* bias1  = (const float*)d_in[8];
    const float* comp2  = (const float*)d_in[9];
    const float* basis2 = (const float*)d_in[10];
    const float* root2  = (const float*)d_in[11];
    const float* bias2  = (const float*)d_in[12];

    int E = in_sizes[1];
    const int* src = edge_index;
    const int* dst = edge_index + E;
    int relrows = in_sizes[3] / DIM;   // 40

    // workspace layout (16B-aligned regions)
    short* Wfb1 = (short*)d_ws;                          // 9*16384 shorts
    short* Wfb2 = Wfb1 + (size_t)9 * 16384;
    ushort* xb  = (ushort*)(Wfb2 + (size_t)9 * 16384);   // 40000*128 bf16
    ushort* hb  = xb + (size_t)NENT * DIM;               // 40000*128 bf16
    ushort* G   = hb + (size_t)NENT * DIM;               // 20480*1024 bf16 (42 MB)
    int* hist   = (int*)(G + (size_t)P0END * 1024);      // 40000 (pad 40004)
    int* offs   = hist + 40004;                          // 40001 (pad 40004)
    int* cursor = offs + 40004;                          // 40000 (pad 40004)
    int* bsum   = cursor + 40004;                        // 157 (pad 160)
    unsigned* packed = (unsigned*)(bsum + 160);          // E

    float* outx = (float*)d_out;
    float* outr = outx + (size_t)NENT * DIM;

    hipMemsetAsync(hist, 0, NENT * sizeof(int), stream);

    k_tobf<<<(NENT * DIM / 4 + 255) / 256, 256, 0, stream>>>(init_embed, xb, NENT * DIM);
    k_wfrag9<<<(9 * 16384 + 255) / 256, 256, 0, stream>>>(basis1, root1, Wfb1);
    k_wfrag9<<<(9 * 16384 + 255) / 256, 256, 0, stream>>>(basis2, root2, Wfb2);
    k_hist<<<(E + 255) / 256, 256, 0, stream>>>(dst, E, hist);
    k_scan1<<<SCANBLK, 256, 0, stream>>>(hist, offs, bsum);
    k_scan2<<<1, 256, 0, stream>>>(bsum);
    k_scan3<<<SCANBLK, 256, 0, stream>>>(offs, cursor, bsum, E);
    k_scatter<<<(E + 255) / 256, 256, 0, stream>>>(edge_type, src, dst, E, cursor, packed);

    // layer 1: hb = bf16(tanh(G@W~1 + x@root1 + bias1)), two node passes
    k_gather<<<P0END / 4, 256, 0, stream>>>(xb, packed, offs, comp1, G, 0, P0END);
    k_bgemm<<<P0END / 64, 256, 0, stream>>>(G, xb, Wfb1, bias1, hb, outx, 0, 1);
    k_gather<<<(NENT - P0END) / 4, 256, 0, stream>>>(xb, packed, offs, comp1, G, P0END, NENT);
    k_bgemm<<<(NENT - P0END) / 64, 256, 0, stream>>>(G, xb, Wfb1, bias1, hb, outx, P0END, 1);

    // layer 2: out = G@W~2 + h@root2 + bias2 (f32 to d_out)
    k_gather<<<P0END / 4, 256, 0, stream>>>(hb, packed, offs, comp2, G, 0, P0END);
    k_bgemm<<<P0END / 64, 256, 0, stream>>>(G, hb, Wfb2, bias2, hb, outx, 0, 0);
    k_gather<<<(NENT - P0END) / 4, 256, 0, stream>>>(hb, packed, offs, comp2, G, P0END, NENT);
    k_bgemm<<<(NENT - P0END) / 64, 256, 0, stream>>>(G, hb, Wfb2, bias2, hb, outx, P0END, 0);

    // relation output: r = init_rel @ w_rel
    k_rel<<<(relrows * DIM + 255) / 256, 256, 0, stream>>>(init_rel, w_rel, outr, relrows);
}

// Round 8
// 324.966 us; speedup vs baseline: 4.7607x; 1.5696x over previous
//
#include <hip/hip_runtime.h>
#include <hip/hip_bf16.h>

#define NENT 40000
#define NREL 20
#define DIM 128
#define NBASIS 8
#define KTOT 1152              // 8*128 (G) + 128 (x)
#define P0END 20480            // pass split (320 tiles of 64)
#define SCANBLK 157            // ceil(40000/256)

typedef __attribute__((ext_vector_type(8))) short sh8;
typedef __attribute__((ext_vector_type(4))) float fx4;

__device__ __forceinline__ short f2bf(float f) {
    union { __hip_bfloat16 h; short s; } u;
    u.h = __float2bfloat16(f);
    return u.s;
}

// f32 -> bf16 copy (x panel for layer 1 + gather source)
__global__ void k_tobf(const float* __restrict__ x, ushort* __restrict__ xb, int nelem) {
    int i = (blockIdx.x * 256 + threadIdx.x) * 4;
    if (i >= nelem) return;
    float4 v = *(const float4*)(x + i);
    ushort4 o;
    o.x = (ushort)f2bf(v.x); o.y = (ushort)f2bf(v.y);
    o.z = (ushort)f2bf(v.z); o.w = (ushort)f2bf(v.w);
    *(ushort4*)(xb + i) = o;
}

// Fragment-order stacked B: ks 0..7 = basis[ks] (k-rows i), ks 8 = root.
// B-frag: lane holds B[k = kk*32 + lhi*8 + e][col = c*16 + l15].
__global__ void k_wfrag9(const float* __restrict__ basis, const float* __restrict__ root,
                         short* __restrict__ Wfb) {
    int t = blockIdx.x * 256 + threadIdx.x;
    if (t >= 9 * 16384) return;
    int ks = t / 16384;
    int rem = t & 16383;
    int i = rem >> 7, o = rem & 127;
    float v = (ks < 8) ? basis[ks * 16384 + i * 128 + o] : root[i * 128 + o];
    int c = o >> 4, l15 = o & 15;
    int kk = i >> 5, lhi = (i >> 3) & 3, e = i & 7;
    int lane = l15 + lhi * 16;
    Wfb[(size_t)ks * 16384 + (size_t)(((c * 4 + kk) * 64 + lane) << 3) + e] = f2bf(v);
}

__global__ void k_hist(const int* __restrict__ dst, int E, int* __restrict__ hist) {
    int e = blockIdx.x * 256 + threadIdx.x;
    if (e < E) atomicAdd(&hist[dst[e]], 1);
}

// -------- 3-phase parallel scan over NENT bins --------
__global__ void k_scan1(const int* __restrict__ hist, int* __restrict__ offs,
                        int* __restrict__ bsum) {
    __shared__ int ps[256];
    int t = threadIdx.x;
    int i = blockIdx.x * 256 + t;
    int v = (i < NENT) ? hist[i] : 0;
    ps[t] = v;
    __syncthreads();
    for (int off = 1; off < 256; off <<= 1) {
        int u = (t >= off) ? ps[t - off] : 0;
        __syncthreads();
        ps[t] += u;
        __syncthreads();
    }
    if (i < NENT) offs[i] = ps[t] - v;
    if (t == 255) bsum[blockIdx.x] = ps[255];
}

__global__ void k_scan2(int* __restrict__ bsum) {
    __shared__ int ps[256];
    int t = threadIdx.x;
    int v = (t < SCANBLK) ? bsum[t] : 0;
    ps[t] = v;
    __syncthreads();
    for (int off = 1; off < 256; off <<= 1) {
        int u = (t >= off) ? ps[t - off] : 0;
        __syncthreads();
        ps[t] += u;
        __syncthreads();
    }
    if (t < SCANBLK) bsum[t] = ps[t] - v;
}

__global__ void k_scan3(int* __restrict__ offs, int* __restrict__ cursor,
                        const int* __restrict__ bsum, int E) {
    int i = blockIdx.x * 256 + threadIdx.x;
    if (i < NENT) {
        int o = offs[i] + bsum[blockIdx.x];
        offs[i] = o;
        cursor[i] = o;
    }
    if (i == 0) offs[NENT] = E;
}

// counting-sort by dst: packed = src | et<<16
__global__ void k_scatter(const int* __restrict__ et, const int* __restrict__ srcA,
                          const int* __restrict__ dstA, int E,
                          int* __restrict__ cursor, unsigned* __restrict__ packed) {
    int e = blockIdx.x * 256 + threadIdx.x;
    if (e >= E) return;
    int pos = atomicAdd(&cursor[dstA[e]], 1);
    packed[pos] = (unsigned)srcA[e] | ((unsigned)et[e] << 16);
}

// One wave per dst node: G[n][b][:] = (1/deg) * sum_e comp[et,b]*x[src].
__global__ __launch_bounds__(256) void k_gather(
    const ushort* __restrict__ xb, const unsigned* __restrict__ packed,
    const int* __restrict__ offs, const float* __restrict__ comp,
    ushort* __restrict__ G, int n0, int n1) {
    __shared__ __align__(16) float cl[NREL * NBASIS];
    int t = threadIdx.x;
    if (t < NREL * NBASIS) cl[t] = comp[t];
    __syncthreads();
    int n = n0 + blockIdx.x * 4 + (t >> 6);
    if (n >= n1) return;
    int lane = t & 63;
    int beg = offs[n];
    int cnt = offs[n + 1] - beg;

    float a0[NBASIS], a1[NBASIS];
#pragma unroll
    for (int b = 0; b < NBASIS; ++b) { a0[b] = 0.f; a1[b] = 0.f; }

    const unsigned* xrow = (const unsigned*)xb + lane;
    unsigned pA = 0, pB = 0, rA = 0;
    if (cnt > 0) { pA = packed[beg]; rA = xrow[(size_t)(pA & 0xFFFFu) * 64]; }
    if (cnt > 1) pB = packed[beg + 1];

    for (int i = 0; i < cnt; ++i) {
        unsigned pC = (i + 2 < cnt) ? packed[beg + i + 2] : 0u;
        unsigned rB = xrow[(size_t)(pB & 0xFFFFu) * 64];
        float xlo = __uint_as_float(rA << 16);
        float xhi = __uint_as_float(rA & 0xFFFF0000u);
        int et = pA >> 16;
        float4 cwa = *(const float4*)&cl[et * NBASIS];
        float4 cwb = *(const float4*)&cl[et * NBASIS + 4];
        a0[0] += cwa.x * xlo; a1[0] += cwa.x * xhi;
        a0[1] += cwa.y * xlo; a1[1] += cwa.y * xhi;
        a0[2] += cwa.z * xlo; a1[2] += cwa.z * xhi;
        a0[3] += cwa.w * xlo; a1[3] += cwa.w * xhi;
        a0[4] += cwb.x * xlo; a1[4] += cwb.x * xhi;
        a0[5] += cwb.y * xlo; a1[5] += cwb.y * xhi;
        a0[6] += cwb.z * xlo; a1[6] += cwb.z * xhi;
        a0[7] += cwb.w * xlo; a1[7] += cwb.w * xhi;
        pA = pB; pB = pC; rA = rB;
    }

    float inv = 1.f / (float)(cnt < 1 ? 1 : cnt);
    unsigned* go = (unsigned*)(G + (size_t)(n - n0) * 1024) + lane;
#pragma unroll
    for (int b = 0; b < NBASIS; ++b) {
        unsigned lo = (unsigned)(ushort)f2bf(a0[b] * inv);
        unsigned hi = (unsigned)(ushort)f2bf(a1[b] * inv);
        go[b * 64] = lo | (hi << 16);
    }
}

// Dense MFMA GEMM, register-pipelined: C[64 x 128] = [G | xpan] @ Wfb + bias.
// 2x2 wave grid: wave = 32 rows x 64 cols. A+B double-buffered in registers
// across the 9 K-slices; ~32 loads in flight, no LDS.
__global__ __launch_bounds__(256) void k_bgemm(
    const ushort* __restrict__ G, const ushort* __restrict__ xpan,
    const short* __restrict__ Wfb, const float* __restrict__ bias,
    ushort* __restrict__ outbf, float* __restrict__ outf, int n0, int act) {
    int t = threadIdx.x;
    int lane = t & 63, wid = t >> 6;
    int wr = wid >> 1, wc = wid & 1;          // 2x2 wave grid
    int l15 = lane & 15, lhi = lane >> 4;
    int wc4 = wc * 4;

    int row0 = n0 + blockIdx.x * 64 + wr * 32;       // wave's first row
    const ushort* Ar0 = G + (size_t)(row0 - n0 + l15) * 1024 + lhi * 8;
    const ushort* Ar1 = Ar0 + (size_t)16 * 1024;
    const ushort* Xr0 = xpan + (size_t)(row0 + l15) * 128 + lhi * 8;
    const ushort* Xr1 = Xr0 + (size_t)16 * 128;

    fx4 acc[2][4];
#pragma unroll
    for (int rg = 0; rg < 2; ++rg)
#pragma unroll
        for (int c = 0; c < 4; ++c) acc[rg][c] = (fx4){0.f, 0.f, 0.f, 0.f};

    auto loadA = [&](sh8 (&a)[2][4], int ks) {
        if (ks < 8) {
#pragma unroll
            for (int kk = 0; kk < 4; ++kk) {
                a[0][kk] = *(const sh8*)(Ar0 + ks * 128 + kk * 32);
                a[1][kk] = *(const sh8*)(Ar1 + ks * 128 + kk * 32);
            }
        } else {
#pragma unroll
            for (int kk = 0; kk < 4; ++kk) {
                a[0][kk] = *(const sh8*)(Xr0 + kk * 32);
                a[1][kk] = *(const sh8*)(Xr1 + kk * 32);
            }
        }
    };
    auto loadB = [&](sh8 (&b)[4][4], int ks) {
        const sh8* W8 = (const sh8*)(Wfb + (size_t)ks * 16384);
#pragma unroll
        for (int c = 0; c < 4; ++c)
#pragma unroll
            for (int kk = 0; kk < 4; ++kk)
                b[c][kk] = W8[((wc4 + c) * 4 + kk) * 64 + lane];
    };
    auto step = [&](const sh8 (&a)[2][4], const sh8 (&b)[4][4]) {
#pragma unroll
        for (int rg = 0; rg < 2; ++rg)
#pragma unroll
            for (int c = 0; c < 4; ++c)
#pragma unroll
                for (int kk = 0; kk < 4; ++kk)
                    acc[rg][c] = __builtin_amdgcn_mfma_f32_16x16x32_bf16(
                        a[rg][kk], b[c][kk], acc[rg][c], 0, 0, 0);
    };

    sh8 aA[2][4], aB[2][4], bA[4][4], bB[4][4];
    loadA(aA, 0); loadB(bA, 0);
    loadA(aB, 1); loadB(bB, 1); step(aA, bA);
    loadA(aA, 2); loadB(bA, 2); step(aB, bB);
    loadA(aB, 3); loadB(bB, 3); step(aA, bA);
    loadA(aA, 4); loadB(bA, 4); step(aB, bB);
    loadA(aB, 5); loadB(bB, 5); step(aA, bA);
    loadA(aA, 6); loadB(bA, 6); step(aB, bB);
    loadA(aB, 7); loadB(bB, 7); step(aA, bA);
    loadA(aA, 8); loadB(bA, 8); step(aB, bB);
    step(aA, bA);

    int orow0 = row0 + lhi * 4;   // + rg*16 + j
#pragma unroll
    for (int rg = 0; rg < 2; ++rg) {
#pragma unroll
        for (int c = 0; c < 4; ++c) {
            int col = wc * 64 + c * 16 + l15;
            float bv = bias[col];
#pragma unroll
            for (int j = 0; j < 4; ++j) {
                float v = acc[rg][c][j] + bv;
                if (act) {
                    v = tanhf(v);
                    outbf[(size_t)(orow0 + rg * 16 + j) * 128 + col] = (ushort)f2bf(v);
                } else {
                    outf[(size_t)(orow0 + rg * 16 + j) * 128 + col] = v;
                }
            }
        }
    }
}

__global__ void k_rel(const float* __restrict__ rel, const float* __restrict__ wrel,
                      float* __restrict__ out, int nrows) {
    int idx = blockIdx.x * 256 + threadIdx.x;
    if (idx >= nrows * DIM) return;
    int j = idx >> 7, o = idx & 127;
    float s = 0.f;
    for (int i = 0; i < DIM; ++i) s += rel[j * DIM + i] * wrel[i * DIM + o];
    out[idx] = s;
}

extern "C" void kernel_launch(void* const* d_in, const int* in_sizes, int n_in,
                              void* d_out, int out_size, void* d_ws, size_t ws_size,
                              hipStream_t stream) {
    const int* edge_index = (const int*)d_in[0];
    const int* edge_type  = (const int*)d_in[1];
    const float* init_embed = (const float*)d_in[2];
    const float* init_rel   = (const float*)d_in[3];
    const float* w_rel      = (const float*)d_in[4];
    const float* comp1  = (const float*)d_in[5];
    const float* basis1 = (const float*)d_in[6];
    const float* root1  = (const float*)d_in[7];
    const float* bias1  = (const float*)d_in[8];
    const float* comp2  = (const float*)d_in[9];
    const float* basis2 = (const float*)d_in[10];
    const float* root2  = (const float*)d_in[11];
    const float* bias2  = (const float*)d_in[12];

    int E = in_sizes[1];
    const int* src = edge_index;
    const int* dst = edge_index + E;
    int relrows = in_sizes[3] / DIM;   // 40

    // workspace layout (16B-aligned regions)
    short* Wfb1 = (short*)d_ws;                          // 9*16384 shorts
    short* Wfb2 = Wfb1 + (size_t)9 * 16384;
    ushort* xb  = (ushort*)(Wfb2 + (size_t)9 * 16384);   // 40000*128 bf16
    ushort* hb  = xb + (size_t)NENT * DIM;               // 40000*128 bf16
    ushort* G   = hb + (size_t)NENT * DIM;               // 20480*1024 bf16 (42 MB)
    int* hist   = (int*)(G + (size_t)P0END * 1024);      // 40000 (pad 40004)
    int* offs   = hist + 40004;
    int* cursor = offs + 40004;
    int* bsum   = cursor + 40004;                        // 157 (pad 160)
    unsigned* packed = (unsigned*)(bsum + 160);          // E

    float* outx = (float*)d_out;
    float* outr = outx + (size_t)NENT * DIM;

    hipMemsetAsync(hist, 0, NENT * sizeof(int), stream);

    k_tobf<<<(NENT * DIM / 4 + 255) / 256, 256, 0, stream>>>(init_embed, xb, NENT * DIM);
    k_wfrag9<<<(9 * 16384 + 255) / 256, 256, 0, stream>>>(basis1, root1, Wfb1);
    k_wfrag9<<<(9 * 16384 + 255) / 256, 256, 0, stream>>>(basis2, root2, Wfb2);
    k_hist<<<(E + 255) / 256, 256, 0, stream>>>(dst, E, hist);
    k_scan1<<<SCANBLK, 256, 0, stream>>>(hist, offs, bsum);
    k_scan2<<<1, 256, 0, stream>>>(bsum);
    k_scan3<<<SCANBLK, 256, 0, stream>>>(offs, cursor, bsum, E);
    k_scatter<<<(E + 255) / 256, 256, 0, stream>>>(edge_type, src, dst, E, cursor, packed);

    // layer 1: hb = bf16(tanh(G@W~1 + x@root1 + bias1)), two node passes
    k_gather<<<P0END / 4, 256, 0, stream>>>(xb, packed, offs, comp1, G, 0, P0END);
    k_bgemm<<<P0END / 64, 256, 0, stream>>>(G, xb, Wfb1, bias1, hb, outx, 0, 1);
    k_gather<<<(NENT - P0END) / 4, 256, 0, stream>>>(xb, packed, offs, comp1, G, P0END, NENT);
    k_bgemm<<<(NENT - P0END) / 64, 256, 0, stream>>>(G, xb, Wfb1, bias1, hb, outx, P0END, 1);

    // layer 2: out = G@W~2 + h@root2 + bias2 (f32 to d_out)
    k_gather<<<P0END / 4, 256, 0, stream>>>(hb, packed, offs, comp2, G, 0, P0END);
    k_bgemm<<<P0END / 64, 256, 0, stream>>>(G, hb, Wfb2, bias2, hb, outx, 0, 0);
    k_gather<<<(NENT - P0END) / 4, 256, 0, stream>>>(hb, packed, offs, comp2, G, P0END, NENT);
    k_bgemm<<<(NENT - P0END) / 64, 256, 0, stream>>>(G, hb, Wfb2, bias2, hb, outx, P0END, 0);

    // relation output: r = init_rel @ w_rel
    k_rel<<<(relrows * DIM + 255) / 256, 256, 0, stream>>>(init_rel, w_rel, outr, relrows);
}